// Round 17
// baseline (243.454 us; speedup 1.0000x reference)
//
#include <hip/hip_runtime.h>
#include <hip/hip_bf16.h>

#define N_HEAD 8
#define D_MODEL 512
#define D_HEAD 64
#define D_HIDDEN 2048
#define NTOK 64
#define BATCH 4096

typedef __attribute__((ext_vector_type(4))) float f32x4;
typedef __attribute__((ext_vector_type(8))) short short8;
typedef __attribute__((ext_vector_type(8))) unsigned short u16x8;
typedef __attribute__((ext_vector_type(4))) unsigned short u16x4;

__device__ __forceinline__ float bf2f(unsigned short u) {
    return __uint_as_float(((unsigned int)u) << 16);
}
__device__ __forceinline__ unsigned short f2bf(float f) {
    unsigned int b = __float_as_uint(f);
    b += 0x7fffu + ((b >> 16) & 1u);
    return (unsigned short)(b >> 16);
}
__device__ __forceinline__ float wave_sum(float v) {
    v += __shfl_xor(v, 32); v += __shfl_xor(v, 16); v += __shfl_xor(v, 8);
    v += __shfl_xor(v, 4);  v += __shfl_xor(v, 2);  v += __shfl_xor(v, 1);
    return v;
}
__device__ __forceinline__ void gload_lds16(const void* g, void* l) {
    __builtin_amdgcn_global_load_lds(
        (const __attribute__((address_space(1))) unsigned int*)g,
        (__attribute__((address_space(3))) unsigned int*)l, 16, 0, 0);
}

// ---------------------------------------------------------------------------
// K0: merged prep. y=0..2: transpose {Wv,W1,W2} f32 -> bf16 (N x K);
// y=3: uT[16][512] bf16, uT[h][c] = sum_d Wk[c][h*64+d]*score_w[h][d],
// heads 8..15 zero (per-head consts cancel in softmax; bk/score_b unused).
// ---------------------------------------------------------------------------
__global__ __launch_bounds__(256) void prep_all(
    const float* __restrict__ Wk, const float* __restrict__ score_w,
    const float* __restrict__ Wv, const float* __restrict__ W1,
    const float* __restrict__ W2,
    unsigned short* __restrict__ uT,
    unsigned short* __restrict__ WvT, unsigned short* __restrict__ W1T,
    unsigned short* __restrict__ W2T) {
    int m = blockIdx.y;
    if (m == 3) {
        int idx = blockIdx.x * 256 + threadIdx.x;
        if (idx < 16 * 512) {
            int h = idx & 15, c = idx >> 4;
            float s = 0.f;
            if (h < 8) {
                #pragma unroll 8
                for (int d = 0; d < D_HEAD; ++d)
                    s += Wk[c * D_MODEL + h * D_HEAD + d] * score_w[h * D_HEAD + d];
            }
            uT[h * D_MODEL + c] = f2bf(s);
        }
        return;
    }
    const float* in; unsigned short* out; int K, N, tX, tiles;
    if (m == 0)      { in = Wv; out = WvT; K = 512;  N = 512;  tX = 16; tiles = 256;  }
    else if (m == 1) { in = W1; out = W1T; K = 512;  N = 2048; tX = 64; tiles = 1024; }
    else             { in = W2; out = W2T; K = 2048; N = 512;  tX = 16; tiles = 1024; }
    int t = blockIdx.x;
    if (t >= tiles) return;
    int n0 = (t % tX) * 32, k0 = (t / tX) * 32;
    __shared__ float tile[32][33];
    int tx = threadIdx.x & 31, ty = threadIdx.x >> 5;
    #pragma unroll
    for (int i = ty; i < 32; i += 8)
        tile[i][tx] = in[(size_t)(k0 + i) * N + n0 + tx];
    __syncthreads();
    #pragma unroll
    for (int i = ty; i < 32; i += 8)
        out[(size_t)(n0 + i) * K + k0 + tx] = f2bf(tile[tx][i]);
}

// ---------------------------------------------------------------------------
// K1 v17 = v14 with the pool's x-reads moved OFF the LDS pipe: pool re-reads
// x directly from global as f32 (lines are L2-hot — fetched by stage in the
// SAME iteration; grid sized 512 blocks = 2/CU so per-XCD live set ~4 MB =
// L2).  xl feeds ONLY the score MFMA.  el double-buffered by tile parity,
// zacc by batch parity (assign-at-q0) -> barrier C dropped (2 barriers/qtr).
// Race analysis: all score xl-reads < barB (lgkmcnt); stage(i+1) writes >
// barB exit.  pool(i) el-reads < its barA(i+1) arrival (lgkmcnt covers
// ds_read); score(i+2) rewrites el[i&1] after barA(i+2).  Pool math is now
// exact f32 (x uncompressed).  512 blocks x 512 thr (8 waves), 8 batches/
// block, ~25 KB LDS, 2 blocks/CU.  Stage/score identical to v14.
// ---------------------------------------------------------------------------
__global__ void score_pool_v17(
    const float* __restrict__ x, const unsigned short* __restrict__ uT,
    unsigned short* __restrict__ pooled) {
    __shared__ unsigned short xl[16 * D_MODEL];   // 16 KB quarter tile (score only)
    __shared__ unsigned short ul[8 * D_MODEL];    // 8 KB swizzled uT rows 0..7
    __shared__ float el[2][16 * 8];               // 1 KB e[t][h], tile parity
    __shared__ float zacc[2][8];                  // 64 B Z per head, batch parity

    const int tid = threadIdx.x;                  // 0..511
    const int l = tid & 63, w = tid >> 6;         // 8 waves
    const int hg = l >> 4, lr = l & 15;

    // ul init: 8 rows x 512 ch, one u16x8 per thread, swizzled like xl rows
    {
        int r = tid >> 6;                  // 0..7
        int c8 = (tid & 63) * 8;
        u16x8 v = *(const u16x8*)(uT + r * D_MODEL + c8);
        *(u16x8*)&ul[r * D_MODEL + (c8 ^ (r << 3))] = v;
    }

    // staging geometry (lane-consecutive): float4 #(j*512+tid) of 16x512 tile
    const int tr4 = tid >> 7;              // row = j*4 + tr4
    const int col4 = (tid & 127) * 4;

    // pool geometry: thread = channel pair (2*cpair, +1) x head quad (hh)
    const int cpair = tid & 255;
    const int hh = tid >> 8;               // 0/1 -> heads hh*4..hh*4+3

    const int b0 = blockIdx.x * 8;

    float4 pre[4];
    {   // prologue: quarter 0 of batch b0
        const float4* p = (const float4*)(x + (size_t)b0 * (NTOK * D_MODEL));
        #pragma unroll
        for (int j = 0; j < 4; ++j) pre[j] = p[j * 512 + tid];
    }

    f32x4 acc0 = {0.f, 0.f, 0.f, 0.f};     // channel 2*cpair,   heads hh*4..+4
    f32x4 acc1 = {0.f, 0.f, 0.f, 0.f};     // channel 2*cpair+1, heads hh*4..+4

    #pragma unroll 1
    for (int qq = 0; qq < 32; ++qq) {
        const int q = qq & 3;
        const int bb = qq >> 2;            // batch index within block
        // ---- stage: regs -> swizzled bf16 LDS (4 x b64 writes) ----
        #pragma unroll
        for (int j = 0; j < 4; ++j) {
            int row = j * 4 + tr4;
            float4 a = pre[j];
            u16x4 ov = {f2bf(a.x), f2bf(a.y), f2bf(a.z), f2bf(a.w)};
            *(u16x4*)&xl[row * D_MODEL + (col4 ^ ((row & 7) << 3))] = ov;
        }
        // issue next quarter's loads (stay in flight across barriers)
        if (qq < 31) {
            const int nb = b0 + ((qq + 1) >> 2), nq = (qq + 1) & 3;
            const float4* p = (const float4*)(x + (size_t)nb * (NTOK * D_MODEL) +
                                              nq * 16 * D_MODEL);
            #pragma unroll
            for (int j = 0; j < 4; ++j) pre[j] = p[j * 512 + tid];
        }
        asm volatile("s_waitcnt lgkmcnt(0)" ::: "memory");
        __builtin_amdgcn_s_barrier();                                    // A

        // ---- score: one rotating wave does 16 MFMAs + exp + Z ----
        if (w == (qq & 7)) {
            f32x4 sacc = {0.f, 0.f, 0.f, 0.f};
            const int rbase = lr * D_MODEL;
            const int rsw = (lr & 7) << 3;
            #pragma unroll
            for (int ks = 0; ks < 16; ++ks) {
                int off = ks * 32 + hg * 8;
                short8 uf;
                if (lr < 8) uf = *(const short8*)&ul[lr * D_MODEL + (off ^ (lr << 3))];
                else        uf = (short8){0, 0, 0, 0, 0, 0, 0, 0};
                short8 xf = *(const short8*)&xl[rbase + (off ^ rsw)];
                sacc = __builtin_amdgcn_mfma_f32_16x16x32_bf16(uf, xf, sacc, 0, 0, 0);
            }
            f32x4 ev;
            float zsum[4];
            #pragma unroll
            for (int j = 0; j < 4; ++j) {
                float e = __expf(sacc[j]);   // scores O(0.1): no max subtraction
                ev[j] = e;
                e += __shfl_xor(e, 1); e += __shfl_xor(e, 2);
                e += __shfl_xor(e, 4); e += __shfl_xor(e, 8);
                zsum[j] = e;
            }
            if (hg < 2) {
                *(f32x4*)&el[qq & 1][lr * 8 + hg * 4] = ev;
                if (lr == 0) {
                    const int zb = bb & 1;
                    f32x4 z;
                    if (q == 0) {
                        z = (f32x4){zsum[0], zsum[1], zsum[2], zsum[3]};
                    } else {
                        z = *(const f32x4*)&zacc[zb][hg * 4];
                        z[0] += zsum[0]; z[1] += zsum[1];
                        z[2] += zsum[2]; z[3] += zsum[3];
                    }
                    *(f32x4*)&zacc[zb][hg * 4] = z;
                }
            }
        }
        asm volatile("s_waitcnt lgkmcnt(0)" ::: "memory");
        __builtin_amdgcn_s_barrier();                                    // B

        // ---- pool: x re-read from global (L2-hot, f32) + el broadcast ----
        {
            const float2* xq = (const float2*)(x + (size_t)(b0 + bb) * (NTOK * D_MODEL) +
                                               (size_t)q * 16 * D_MODEL) + cpair;
            #pragma unroll 4
            for (int tk = 0; tk < 16; ++tk) {
                float2 xv = xq[tk * 256];
                f32x4 e4 = *(const f32x4*)&el[qq & 1][tk * 8 + hh * 4];
                acc0 += e4 * xv.x;
                acc1 += e4 * xv.y;
            }
        }
        // ---- batch end: normalize and write ----
        if (q == 3) {
            f32x4 z = *(const f32x4*)&zacc[bb & 1][hh * 4];
            unsigned short* pb = pooled + (size_t)(b0 + bb) * (N_HEAD * D_MODEL);
            #pragma unroll
            for (int hq = 0; hq < 4; ++hq) {
                float rzq = 1.f / z[hq];
                unsigned int pk = (unsigned int)f2bf(acc0[hq] * rzq) |
                                  ((unsigned int)f2bf(acc1[hq] * rzq) << 16);
                *(unsigned int*)(pb + (hh * 4 + hq) * D_MODEL + cpair * 2) = pk;
            }
            acc0 = (f32x4){0.f, 0.f, 0.f, 0.f};
            acc1 = (f32x4){0.f, 0.f, 0.f, 0.f};
        }
        // no barrier C: pool doesn't read xl; el/zacc double-buffered (see hdr)
    }
}

// ---------------------------------------------------------------------------
// MFMA GEMM (unchanged): global_load_lds staging, XOR-swizzled via
// pre-swizzled global source, 4 waves (2x2).  MODE 0: per-head, bf16+bias.
// MODE 1: bf16, gelu(+bias).  MODE 2: f32, +bias +residual(bf16).
// ---------------------------------------------------------------------------
template <int BM, int BN, int MODE>
__global__ __launch_bounds__(256) void gemm_mf(
    const unsigned short* __restrict__ A, int lda,
    const unsigned short* __restrict__ BT,
    const float* __restrict__ bias,
    void* __restrict__ Cout, int ldc,
    const unsigned short* __restrict__ res, int K) {
    __shared__ unsigned short Al[BM * 64];
    __shared__ unsigned short Bl[BN * 64];
    int m0 = blockIdx.x * BM;
    int n0;
    const unsigned short* Ap = A;
    const unsigned short* Bp;
    const float* bp;
    if (MODE == 0) {
        int h = blockIdx.y;
        Ap = A + (size_t)h * 512;
        Bp = BT + (size_t)h * 64 * K;
        bp = bias + h * 64;
        n0 = h * 64;
    } else {
        n0 = blockIdx.y * BN;
        Bp = BT + (size_t)n0 * K;
        bp = bias + n0;
    }
    int tid = threadIdx.x, l = tid & 63, w = tid >> 6;
    int lr = l & 15, lq = l >> 4;
    int wm = w >> 1, wn = w & 1;
    constexpr int MR = BM / 32, NR = BN / 32;
    constexpr int AI = BM / 8, BI = BN / 8;

    f32x4 acc[MR][NR];
    #pragma unroll
    for (int mi = 0; mi < MR; ++mi)
        #pragma unroll
        for (int nj = 0; nj < NR; ++nj) acc[mi][nj] = (f32x4){0.f, 0.f, 0.f, 0.f};

    int srow = l >> 3;
    int scol = ((l & 7) ^ ((l >> 3) & 7)) << 3;

    for (int k0 = 0; k0 < K; k0 += 64) {
        #pragma unroll
        for (int j = 0; j < AI / 4; ++j) {
            int ji = w * (AI / 4) + j;
            const unsigned short* src = Ap + (size_t)(m0 + ji * 8 + srow) * lda + k0 + scol;
            gload_lds16(src, &Al[ji * 512]);
        }
        #pragma unroll
        for (int j = 0; j < BI / 4; ++j) {
            int ji = w * (BI / 4) + j;
            const unsigned short* src = Bp + (size_t)(ji * 8 + srow) * K + k0 + scol;
            gload_lds16(src, &Bl[ji * 512]);
        }
        __syncthreads();
        #pragma unroll
        for (int kk = 0; kk < 64; kk += 32) {
            int sw = (kk + lq * 8) ^ ((l & 7) << 3);
            short8 af[MR], bf[NR];
            #pragma unroll
            for (int mi = 0; mi < MR; ++mi)
                af[mi] = *(const short8*)&Al[(wm * (BM / 2) + mi * 16 + lr) * 64 + sw];
            #pragma unroll
            for (int nj = 0; nj < NR; ++nj)
                bf[nj] = *(const short8*)&Bl[(wn * (BN / 2) + nj * 16 + lr) * 64 + sw];
            #pragma unroll
            for (int mi = 0; mi < MR; ++mi)
                #pragma unroll
                for (int nj = 0; nj < NR; ++nj)
                    acc[mi][nj] = __builtin_amdgcn_mfma_f32_16x16x32_bf16(
                        af[mi], bf[nj], acc[mi][nj], 0, 0, 0);
        }
        __syncthreads();
    }

    #pragma unroll
    for (int mi = 0; mi < MR; ++mi) {
        #pragma unroll
        for (int nj = 0; nj < NR; ++nj) {
            #pragma unroll
            for (int j = 0; j < 4; ++j) {
                int row = m0 + wm * (BM / 2) + mi * 16 + lq * 4 + j;
                int nl = wn * (BN / 2) + nj * 16 + lr;
                int col = n0 + nl;
                float v = acc[mi][nj][j] + bp[nl];
                if (MODE == 1) {
                    v = 0.5f * v * (1.0f + erff(v * 0.70710678118654752f));
                }
                if (MODE == 2) {
                    v += bf2f(res[(size_t)row * 512 + col]);
                    ((float*)Cout)[(size_t)row * ldc + col] = v;
                } else {
                    ((unsigned short*)Cout)[(size_t)row * ldc + col] = f2bf(v);
                }
            }
        }
    }
}

// ---------------------------------------------------------------------------
// K5: in-place LayerNorm over 512, one wave per row
// ---------------------------------------------------------------------------
__global__ __launch_bounds__(256) void ln_kernel(
    float* __restrict__ y, const float* __restrict__ g, const float* __restrict__ bta) {
    int row = blockIdx.x * 4 + (threadIdx.x >> 6);
    int l = threadIdx.x & 63;
    float* yp = y + (size_t)row * D_MODEL;
    float4 v0 = *(const float4*)(yp + l * 8);
    float4 v1 = *(const float4*)(yp + l * 8 + 4);
    float vv[8] = {v0.x, v0.y, v0.z, v0.w, v1.x, v1.y, v1.z, v1.w};
    float s = 0.f;
    #pragma unroll
    for (int i = 0; i < 8; ++i) s += vv[i];
    s = wave_sum(s);
    float mean = s * (1.f / 512.f);
    float q = 0.f;
    #pragma unroll
    for (int i = 0; i < 8; ++i) { float d = vv[i] - mean; q += d * d; }
    q = wave_sum(q);
    float rstd = rsqrtf(q * (1.f / 512.f) + 1e-5f);
    float4 g0 = *(const float4*)(g + l * 8);
    float4 g1 = *(const float4*)(g + l * 8 + 4);
    float4 b0 = *(const float4*)(bta + l * 8);
    float4 b1 = *(const float4*)(bta + l * 8 + 4);
    float gv[8] = {g0.x, g0.y, g0.z, g0.w, g1.x, g1.y, g1.z, g1.w};
    float bv[8] = {b0.x, b0.y, b0.z, b0.w, b1.x, b1.y, b1.z, b1.w};
    float ov[8];
    #pragma unroll
    for (int i = 0; i < 8; ++i) ov[i] = (vv[i] - mean) * rstd * gv[i] + bv[i];
    float4 o0 = {ov[0], ov[1], ov[2], ov[3]};
    float4 o1 = {ov[4], ov[5], ov[6], ov[7]};
    *(float4*)(yp + l * 8) = o0;
    *(float4*)(yp + l * 8 + 4) = o1;
}

extern "C" void kernel_launch(void* const* d_in, const int* in_sizes, int n_in,
                              void* d_out, int out_size, void* d_ws, size_t ws_size,
                              hipStream_t stream) {
    const float* x       = (const float*)d_in[0];
    const float* Wk      = (const float*)d_in[1];
    const float* Wv      = (const float*)d_in[3];
    const float* bv      = (const float*)d_in[4];
    const float* score_w = (const float*)d_in[5];
    const float* W1      = (const float*)d_in[7];
    const float* b1      = (const float*)d_in[8];
    const float* W2      = (const float*)d_in[9];
    const float* b2      = (const float*)d_in[10];
    const float* ln_g    = (const float*)d_in[11];
    const float* ln_b    = (const float*)d_in[12];
    float* out = (float*)d_out;

    char* ws = (char*)d_ws;
    size_t off = 0;
    auto alloc = [&](size_t sz) {
        void* p = ws + off;
        off = (off + sz + 1023) & ~(size_t)1023;
        return p;
    };
    unsigned short* uT  = (unsigned short*)alloc((size_t)16 * D_MODEL * 2);
    unsigned short* WvT = (unsigned short*)alloc((size_t)512 * 512 * 2);
    unsigned short* W1T = (unsigned short*)alloc((size_t)2048 * 512 * 2);
    unsigned short* W2T = (unsigned short*)alloc((size_t)512 * 2048 * 2);
    unsigned short* pooled = (unsigned short*)alloc((size_t)BATCH * N_HEAD * D_MODEL * 2);
    unsigned short* feat   = (unsigned short*)alloc((size_t)BATCH * D_MODEL * 2);
    unsigned short* Hbuf   = (unsigned short*)alloc((size_t)BATCH * D_HIDDEN * 2);

    prep_all<<<dim3(1024, 4), dim3(256), 0, stream>>>(
        Wk, score_w, Wv, W1, W2, uT, WvT, W1T, W2T);
    score_pool_v17<<<dim3(512), dim3(512), 0, stream>>>(x, uT, pooled);
    // proj: feature = pooled @ blockdiag(Wv per head) + bv
    gemm_mf<128, 64, 0><<<dim3(32, 8), dim3(256), 0, stream>>>(
        pooled, N_HEAD * D_MODEL, WvT, bv, (void*)feat, D_MODEL,
        (const unsigned short*)nullptr, 512);
    // ffn1: H = gelu(feature @ W1 + b1)
    gemm_mf<128, 128, 1><<<dim3(32, 16), dim3(256), 0, stream>>>(
        feat, D_MODEL, W1T, b1, (void*)Hbuf, D_HIDDEN,
        (const unsigned short*)nullptr, 512);
    // ffn2: y = H @ W2 + b2 + feature  (f32 -> d_out)
    gemm_mf<64, 128, 2><<<dim3(64, 4), dim3(256), 0, stream>>>(
        Hbuf, D_HIDDEN, W2T, b2, (void*)out, D_MODEL, feat, 2048);
    ln_kernel<<<dim3(1024), dim3(256), 0, stream>>>(out, ln_g, ln_b);
}

// Round 18
// 206.941 us; speedup vs baseline: 1.1764x; 1.1764x over previous
//
#include <hip/hip_runtime.h>
#include <hip/hip_bf16.h>

#define N_HEAD 8
#define D_MODEL 512
#define D_HEAD 64
#define D_HIDDEN 2048
#define NTOK 64
#define BATCH 4096

typedef __attribute__((ext_vector_type(4))) float f32x4;
typedef __attribute__((ext_vector_type(8))) short short8;
typedef __attribute__((ext_vector_type(8))) unsigned short u16x8;
typedef __attribute__((ext_vector_type(4))) unsigned short u16x4;

__device__ __forceinline__ float bf2f(unsigned short u) {
    return __uint_as_float(((unsigned int)u) << 16);
}
__device__ __forceinline__ unsigned short f2bf(float f) {
    unsigned int b = __float_as_uint(f);
    b += 0x7fffu + ((b >> 16) & 1u);
    return (unsigned short)(b >> 16);
}
__device__ __forceinline__ float wave_sum(float v) {
    v += __shfl_xor(v, 32); v += __shfl_xor(v, 16); v += __shfl_xor(v, 8);
    v += __shfl_xor(v, 4);  v += __shfl_xor(v, 2);  v += __shfl_xor(v, 1);
    return v;
}
__device__ __forceinline__ void gload_lds16(const void* g, void* l) {
    __builtin_amdgcn_global_load_lds(
        (const __attribute__((address_space(1))) unsigned int*)g,
        (__attribute__((address_space(3))) unsigned int*)l, 16, 0, 0);
}

// ---------------------------------------------------------------------------
// K0: merged prep. y=0..2: transpose {Wv,W1,W2} f32 -> bf16 (N x K);
// y=3: uT[16][512] bf16, uT[h][c] = sum_d Wk[c][h*64+d]*score_w[h][d],
// heads 8..15 zero (per-head consts cancel in softmax; bk/score_b unused).
// ---------------------------------------------------------------------------
__global__ __launch_bounds__(256) void prep_all(
    const float* __restrict__ Wk, const float* __restrict__ score_w,
    const float* __restrict__ Wv, const float* __restrict__ W1,
    const float* __restrict__ W2,
    unsigned short* __restrict__ uT,
    unsigned short* __restrict__ WvT, unsigned short* __restrict__ W1T,
    unsigned short* __restrict__ W2T) {
    int m = blockIdx.y;
    if (m == 3) {
        int idx = blockIdx.x * 256 + threadIdx.x;
        if (idx < 16 * 512) {
            int h = idx & 15, c = idx >> 4;
            float s = 0.f;
            if (h < 8) {
                #pragma unroll 8
                for (int d = 0; d < D_HEAD; ++d)
                    s += Wk[c * D_MODEL + h * D_HEAD + d] * score_w[h * D_HEAD + d];
            }
            uT[h * D_MODEL + c] = f2bf(s);
        }
        return;
    }
    const float* in; unsigned short* out; int K, N, tX, tiles;
    if (m == 0)      { in = Wv; out = WvT; K = 512;  N = 512;  tX = 16; tiles = 256;  }
    else if (m == 1) { in = W1; out = W1T; K = 512;  N = 2048; tX = 64; tiles = 1024; }
    else             { in = W2; out = W2T; K = 2048; N = 512;  tX = 16; tiles = 1024; }
    int t = blockIdx.x;
    if (t >= tiles) return;
    int n0 = (t % tX) * 32, k0 = (t / tX) * 32;
    __shared__ float tile[32][33];
    int tx = threadIdx.x & 31, ty = threadIdx.x >> 5;
    #pragma unroll
    for (int i = ty; i < 32; i += 8)
        tile[i][tx] = in[(size_t)(k0 + i) * N + n0 + tx];
    __syncthreads();
    #pragma unroll
    for (int i = ty; i < 32; i += 8)
        out[(size_t)(n0 + i) * K + k0 + tx] = f2bf(tile[tx][i]);
}

// ---------------------------------------------------------------------------
// K1 v14 (CHAMPION, 207.7 us total): v9 structure at 512 threads (8 waves),
// halved per-thread state: pre[4] float4, pool slice 2ch x 4heads.  4 blocks/
// CU x 8 waves = 32 waves/CU.  Quarter-batch pipelining, 3 raw s_barriers/
// quarter (lgkmcnt-only waits, loads in flight across), rotating MFMA score
// wave (w == qq&7), pool from swizzled bf16 LDS, no cross-thread pool
// reduce.  1024 blocks x 4 batches.  x read ONCE from HBM.
// ---------------------------------------------------------------------------
__global__ void score_pool_v14(
    const float* __restrict__ x, const unsigned short* __restrict__ uT,
    unsigned short* __restrict__ pooled) {
    __shared__ unsigned short xl[16 * D_MODEL];   // 16 KB quarter tile
    __shared__ unsigned short ul[8 * D_MODEL];    // 8 KB swizzled uT rows 0..7
    __shared__ float el[16 * 8];                  // 512 B unnormalized e[t][h]
    __shared__ float zacc[8];                     // 32 B running Z per head

    const int tid = threadIdx.x;                  // 0..511
    const int l = tid & 63, w = tid >> 6;         // 8 waves
    const int hg = l >> 4, lr = l & 15;

    // ul init: 8 rows x 512 ch, one u16x8 per thread, swizzled like xl rows
    {
        int r = tid >> 6;                  // 0..7
        int c8 = (tid & 63) * 8;
        u16x8 v = *(const u16x8*)(uT + r * D_MODEL + c8);
        *(u16x8*)&ul[r * D_MODEL + (c8 ^ (r << 3))] = v;
    }

    // staging geometry (lane-consecutive): float4 #(j*512+tid) of 16x512 tile
    const int tr4 = tid >> 7;              // row = j*4 + tr4
    const int col4 = (tid & 127) * 4;

    // pool geometry: thread = channel pair c2 x head quad (hh)
    const int c2 = (tid & 255) * 2;
    const int hh = tid >> 8;               // 0/1 -> heads hh*4..hh*4+3

    const int b0 = blockIdx.x * 4;

    float4 pre[4];
    {   // prologue: quarter 0 of batch b0
        const float4* p = (const float4*)(x + (size_t)b0 * (NTOK * D_MODEL));
        #pragma unroll
        for (int j = 0; j < 4; ++j) pre[j] = p[j * 512 + tid];
    }

    f32x4 acc0 = {0.f, 0.f, 0.f, 0.f};     // channel c2,   heads hh*4..+4
    f32x4 acc1 = {0.f, 0.f, 0.f, 0.f};     // channel c2+1, heads hh*4..+4

    #pragma unroll 1
    for (int qq = 0; qq < 16; ++qq) {
        const int q = qq & 3;
        // ---- stage: regs -> swizzled bf16 LDS (4 x b64 writes) ----
        if (q == 0 && tid < 8) zacc[tid] = 0.f;
        #pragma unroll
        for (int j = 0; j < 4; ++j) {
            int row = j * 4 + tr4;
            float4 a = pre[j];
            u16x4 ov = {f2bf(a.x), f2bf(a.y), f2bf(a.z), f2bf(a.w)};
            *(u16x4*)&xl[row * D_MODEL + (col4 ^ ((row & 7) << 3))] = ov;
        }
        // issue next quarter's loads (stay in flight across all barriers)
        if (qq < 15) {
            const int nb = b0 + ((qq + 1) >> 2), nq = (qq + 1) & 3;
            const float4* p = (const float4*)(x + (size_t)nb * (NTOK * D_MODEL) +
                                              nq * 16 * D_MODEL);
            #pragma unroll
            for (int j = 0; j < 4; ++j) pre[j] = p[j * 512 + tid];
        }
        asm volatile("s_waitcnt lgkmcnt(0)" ::: "memory");
        __builtin_amdgcn_s_barrier();                                    // A

        // ---- score: one rotating wave does 16 MFMAs + exp + Z ----
        if (w == (qq & 7)) {
            f32x4 sacc = {0.f, 0.f, 0.f, 0.f};
            const int rbase = lr * D_MODEL;
            const int rsw = (lr & 7) << 3;
            #pragma unroll
            for (int ks = 0; ks < 16; ++ks) {
                int off = ks * 32 + hg * 8;
                short8 uf;
                if (lr < 8) uf = *(const short8*)&ul[lr * D_MODEL + (off ^ (lr << 3))];
                else        uf = (short8){0, 0, 0, 0, 0, 0, 0, 0};
                short8 xf = *(const short8*)&xl[rbase + (off ^ rsw)];
                sacc = __builtin_amdgcn_mfma_f32_16x16x32_bf16(uf, xf, sacc, 0, 0, 0);
            }
            f32x4 ev;
            float zsum[4];
            #pragma unroll
            for (int j = 0; j < 4; ++j) {
                float e = __expf(sacc[j]);   // scores O(0.1): no max subtraction
                ev[j] = e;
                e += __shfl_xor(e, 1); e += __shfl_xor(e, 2);
                e += __shfl_xor(e, 4); e += __shfl_xor(e, 8);
                zsum[j] = e;
            }
            if (hg < 2) {
                *(f32x4*)&el[lr * 8 + hg * 4] = ev;
                if (lr == 0) {
                    f32x4 z = *(const f32x4*)&zacc[hg * 4];
                    z[0] += zsum[0]; z[1] += zsum[1];
                    z[2] += zsum[2]; z[3] += zsum[3];
                    *(f32x4*)&zacc[hg * 4] = z;
                }
            }
        }
        asm volatile("s_waitcnt lgkmcnt(0)" ::: "memory");
        __builtin_amdgcn_s_barrier();                                    // B

        // ---- pool accumulate: all 8 waves, 16 tokens, 2ch x 4h / thread ----
        #pragma unroll 4
        for (int t = 0; t < 16; ++t) {
            unsigned int xw = *(const unsigned int*)&xl[t * D_MODEL +
                                                        (c2 ^ ((t & 7) << 3))];
            f32x4 e4 = *(const f32x4*)&el[t * 8 + hh * 4];   // broadcast
            float xa = __uint_as_float(xw << 16);
            float xb = __uint_as_float(xw & 0xffff0000u);
            acc0 += e4 * xa;
            acc1 += e4 * xb;
        }
        // ---- batch end: normalize and write ----
        if (q == 3) {
            f32x4 z = *(const f32x4*)&zacc[hh * 4];
            unsigned short* pb = pooled + (size_t)(b0 + (qq >> 2)) * (N_HEAD * D_MODEL);
            #pragma unroll
            for (int hq = 0; hq < 4; ++hq) {
                float rzq = 1.f / z[hq];
                unsigned int pk = (unsigned int)f2bf(acc0[hq] * rzq) |
                                  ((unsigned int)f2bf(acc1[hq] * rzq) << 16);
                *(unsigned int*)(pb + (hh * 4 + hq) * D_MODEL + c2) = pk;
            }
            acc0 = (f32x4){0.f, 0.f, 0.f, 0.f};
            acc1 = (f32x4){0.f, 0.f, 0.f, 0.f};
        }
        asm volatile("s_waitcnt lgkmcnt(0)" ::: "memory");
        __builtin_amdgcn_s_barrier();                                    // C
        // xl/el/zacc free for next quarter's stage
    }
}

// ---------------------------------------------------------------------------
// MFMA GEMM (unchanged): global_load_lds staging, XOR-swizzled via
// pre-swizzled global source, 4 waves (2x2).  MODE 0: per-head, bf16+bias.
// MODE 1: bf16, gelu(+bias).  MODE 2: f32, +bias +residual(bf16).
// ---------------------------------------------------------------------------
template <int BM, int BN, int MODE>
__global__ __launch_bounds__(256) void gemm_mf(
    const unsigned short* __restrict__ A, int lda,
    const unsigned short* __restrict__ BT,
    const float* __restrict__ bias,
    void* __restrict__ Cout, int ldc,
    const unsigned short* __restrict__ res, int K) {
    __shared__ unsigned short Al[BM * 64];
    __shared__ unsigned short Bl[BN * 64];
    int m0 = blockIdx.x * BM;
    int n0;
    const unsigned short* Ap = A;
    const unsigned short* Bp;
    const float* bp;
    if (MODE == 0) {
        int h = blockIdx.y;
        Ap = A + (size_t)h * 512;
        Bp = BT + (size_t)h * 64 * K;
        bp = bias + h * 64;
        n0 = h * 64;
    } else {
        n0 = blockIdx.y * BN;
        Bp = BT + (size_t)n0 * K;
        bp = bias + n0;
    }
    int tid = threadIdx.x, l = tid & 63, w = tid >> 6;
    int lr = l & 15, lq = l >> 4;
    int wm = w >> 1, wn = w & 1;
    constexpr int MR = BM / 32, NR = BN / 32;
    constexpr int AI = BM / 8, BI = BN / 8;

    f32x4 acc[MR][NR];
    #pragma unroll
    for (int mi = 0; mi < MR; ++mi)
        #pragma unroll
        for (int nj = 0; nj < NR; ++nj) acc[mi][nj] = (f32x4){0.f, 0.f, 0.f, 0.f};

    int srow = l >> 3;
    int scol = ((l & 7) ^ ((l >> 3) & 7)) << 3;

    for (int k0 = 0; k0 < K; k0 += 64) {
        #pragma unroll
        for (int j = 0; j < AI / 4; ++j) {
            int ji = w * (AI / 4) + j;
            const unsigned short* src = Ap + (size_t)(m0 + ji * 8 + srow) * lda + k0 + scol;
            gload_lds16(src, &Al[ji * 512]);
        }
        #pragma unroll
        for (int j = 0; j < BI / 4; ++j) {
            int ji = w * (BI / 4) + j;
            const unsigned short* src = Bp + (size_t)(ji * 8 + srow) * K + k0 + scol;
            gload_lds16(src, &Bl[ji * 512]);
        }
        __syncthreads();
        #pragma unroll
        for (int kk = 0; kk < 64; kk += 32) {
            int sw = (kk + lq * 8) ^ ((l & 7) << 3);
            short8 af[MR], bf[NR];
            #pragma unroll
            for (int mi = 0; mi < MR; ++mi)
                af[mi] = *(const short8*)&Al[(wm * (BM / 2) + mi * 16 + lr) * 64 + sw];
            #pragma unroll
            for (int nj = 0; nj < NR; ++nj)
                bf[nj] = *(const short8*)&Bl[(wn * (BN / 2) + nj * 16 + lr) * 64 + sw];
            #pragma unroll
            for (int mi = 0; mi < MR; ++mi)
                #pragma unroll
                for (int nj = 0; nj < NR; ++nj)
                    acc[mi][nj] = __builtin_amdgcn_mfma_f32_16x16x32_bf16(
                        af[mi], bf[nj], acc[mi][nj], 0, 0, 0);
        }
        __syncthreads();
    }

    #pragma unroll
    for (int mi = 0; mi < MR; ++mi) {
        #pragma unroll
        for (int nj = 0; nj < NR; ++nj) {
            #pragma unroll
            for (int j = 0; j < 4; ++j) {
                int row = m0 + wm * (BM / 2) + mi * 16 + lq * 4 + j;
                int nl = wn * (BN / 2) + nj * 16 + lr;
                int col = n0 + nl;
                float v = acc[mi][nj][j] + bp[nl];
                if (MODE == 1) {
                    v = 0.5f * v * (1.0f + erff(v * 0.70710678118654752f));
                }
                if (MODE == 2) {
                    v += bf2f(res[(size_t)row * 512 + col]);
                    ((float*)Cout)[(size_t)row * ldc + col] = v;
                } else {
                    ((unsigned short*)Cout)[(size_t)row * ldc + col] = f2bf(v);
                }
            }
        }
    }
}

// ---------------------------------------------------------------------------
// K5: in-place LayerNorm over 512, one wave per row
// ---------------------------------------------------------------------------
__global__ __launch_bounds__(256) void ln_kernel(
    float* __restrict__ y, const float* __restrict__ g, const float* __restrict__ bta) {
    int row = blockIdx.x * 4 + (threadIdx.x >> 6);
    int l = threadIdx.x & 63;
    float* yp = y + (size_t)row * D_MODEL;
    float4 v0 = *(const float4*)(yp + l * 8);
    float4 v1 = *(const float4*)(yp + l * 8 + 4);
    float vv[8] = {v0.x, v0.y, v0.z, v0.w, v1.x, v1.y, v1.z, v1.w};
    float s = 0.f;
    #pragma unroll
    for (int i = 0; i < 8; ++i) s += vv[i];
    s = wave_sum(s);
    float mean = s * (1.f / 512.f);
    float q = 0.f;
    #pragma unroll
    for (int i = 0; i < 8; ++i) { float d = vv[i] - mean; q += d * d; }
    q = wave_sum(q);
    float rstd = rsqrtf(q * (1.f / 512.f) + 1e-5f);
    float4 g0 = *(const float4*)(g + l * 8);
    float4 g1 = *(const float4*)(g + l * 8 + 4);
    float4 b0 = *(const float4*)(bta + l * 8);
    float4 b1 = *(const float4*)(bta + l * 8 + 4);
    float gv[8] = {g0.x, g0.y, g0.z, g0.w, g1.x, g1.y, g1.z, g1.w};
    float bv[8] = {b0.x, b0.y, b0.z, b0.w, b1.x, b1.y, b1.z, b1.w};
    float ov[8];
    #pragma unroll
    for (int i = 0; i < 8; ++i) ov[i] = (vv[i] - mean) * rstd * gv[i] + bv[i];
    float4 o0 = {ov[0], ov[1], ov[2], ov[3]};
    float4 o1 = {ov[4], ov[5], ov[6], ov[7]};
    *(float4*)(yp + l * 8) = o0;
    *(float4*)(yp + l * 8 + 4) = o1;
}

extern "C" void kernel_launch(void* const* d_in, const int* in_sizes, int n_in,
                              void* d_out, int out_size, void* d_ws, size_t ws_size,
                              hipStream_t stream) {
    const float* x       = (const float*)d_in[0];
    const float* Wk      = (const float*)d_in[1];
    const float* Wv      = (const float*)d_in[3];
    const float* bv      = (const float*)d_in[4];
    const float* score_w = (const float*)d_in[5];
    const float* W1      = (const float*)d_in[7];
    const float* b1      = (const float*)d_in[8];
    const float* W2      = (const float*)d_in[9];
    const float* b2      = (const float*)d_in[10];
    const float* ln_g    = (const float*)d_in[11];
    const float* ln_b    = (const float*)d_in[12];
    float* out = (float*)d_out;

    char* ws = (char*)d_ws;
    size_t off = 0;
    auto alloc = [&](size_t sz) {
        void* p = ws + off;
        off = (off + sz + 1023) & ~(size_t)1023;
        return p;
    };
    unsigned short* uT  = (unsigned short*)alloc((size_t)16 * D_MODEL * 2);
    unsigned short* WvT = (unsigned short*)alloc((size_t)512 * 512 * 2);
    unsigned short* W1T = (unsigned short*)alloc((size_t)2048 * 512 * 2);
    unsigned short* W2T = (unsigned short*)alloc((size_t)512 * 2048 * 2);
    unsigned short* pooled = (unsigned short*)alloc((size_t)BATCH * N_HEAD * D_MODEL * 2);
    unsigned short* feat   = (unsigned short*)alloc((size_t)BATCH * D_MODEL * 2);
    unsigned short* Hbuf   = (unsigned short*)alloc((size_t)BATCH * D_HIDDEN * 2);

    prep_all<<<dim3(1024, 4), dim3(256), 0, stream>>>(
        Wk, score_w, Wv, W1, W2, uT, WvT, W1T, W2T);
    score_pool_v14<<<dim3(1024), dim3(512), 0, stream>>>(x, uT, pooled);
    // proj: feature = pooled @ blockdiag(Wv per head) + bv
    gemm_mf<128, 64, 0><<<dim3(32, 8), dim3(256), 0, stream>>>(
        pooled, N_HEAD * D_MODEL, WvT, bv, (void*)feat, D_MODEL,
        (const unsigned short*)nullptr, 512);
    // ffn1: H = gelu(feature @ W1 + b1)
    gemm_mf<128, 128, 1><<<dim3(32, 16), dim3(256), 0, stream>>>(
        feat, D_MODEL, W1T, b1, (void*)Hbuf, D_HIDDEN,
        (const unsigned short*)nullptr, 512);
    // ffn2: y = H @ W2 + b2 + feature  (f32 -> d_out)
    gemm_mf<64, 128, 2><<<dim3(64, 4), dim3(256), 0, stream>>>(
        Hbuf, D_HIDDEN, W2T, b2, (void*)out, D_MODEL, feat, 2048);
    ln_kernel<<<dim3(1024), dim3(256), 0, stream>>>(out, ln_g, ln_b);
}